// Round 1
// baseline (4038.887 us; speedup 1.0000x reference)
//
#include <hip/hip_runtime.h>

#define N_NODES 50000
#define N_EDGES 600000
#define N_GRAPHS 128
#define DIM 128
#define NLAYERS 3
#define NOUT 10

// ---------------------------------------------------------------------------
// copy: agg = x  (float4 grid-stride)
__global__ void copy_f4(float4* __restrict__ dst, const float4* __restrict__ src, int n4) {
    int i = blockIdx.x * blockDim.x + threadIdx.x;
    if (i < n4) dst[i] = src[i];
}

// ---------------------------------------------------------------------------
// scatter-add: agg[dst[e]] += x[src[e]]   (32 threads per edge, float4 each)
__global__ void scatter_edges(float* __restrict__ agg, const float* __restrict__ x,
                              const int* __restrict__ srcs, const int* __restrict__ dsts,
                              int nE) {
    int idx = blockIdx.x * blockDim.x + threadIdx.x;
    int e = idx >> 5;
    if (e >= nE) return;
    int q = idx & 31;
    int s = srcs[e];
    int d = dsts[e];
    const float4 v = ((const float4*)(x + (size_t)s * DIM))[q];
    float* p = agg + (size_t)d * DIM + (q << 2);
    atomicAdd(p + 0, v.x);
    atomicAdd(p + 1, v.y);
    atomicAdd(p + 2, v.z);
    atomicAdd(p + 3, v.w);
}

// ---------------------------------------------------------------------------
// Fused GEMM: out[n][c] = act((in[n]·W[:,c] + b[c]) [* (inv*g[c]) + bt[c]])
// BN=true : BatchNorm(eval) + ReLU epilogue (first MLP linear)
// BN=false: plain bias + ReLU (second MLP linear followed by conv .relu())
// Block: 256 threads = 64 rows x 4 col-groups; thread owns cols {4*j + cg}.
// W (128x128 f32, 64 KB) staged in LDS once per block.
template <bool BN>
__global__ __launch_bounds__(256) void gemm_fused(float* __restrict__ out,
                                                  const float* __restrict__ in,
                                                  const float* __restrict__ W,
                                                  const float* __restrict__ b,
                                                  const float* __restrict__ g,
                                                  const float* __restrict__ bt,
                                                  int nrows) {
    __shared__ float Ws[DIM][DIM];  // 64 KB
    {
        const float4* W4 = (const float4*)W;
        float4* Ws4 = (float4*)&Ws[0][0];
        for (int i = threadIdx.x; i < DIM * DIM / 4; i += 256) Ws4[i] = W4[i];
    }
    __syncthreads();

    const int row = blockIdx.x * 64 + (threadIdx.x >> 2);
    const int cg = threadIdx.x & 3;  // column phase: cols are 4*j + cg (bank-conflict-free LDS reads)
    if (row >= nrows) return;

    const float4* in4 = (const float4*)(in + (size_t)row * DIM);
    float acc[32];
#pragma unroll
    for (int j = 0; j < 32; ++j) acc[j] = 0.f;

#pragma unroll 4
    for (int k4 = 0; k4 < 32; ++k4) {
        const float4 a = in4[k4];
        const float* w0 = &Ws[k4 * 4 + 0][cg];
        const float* w1 = &Ws[k4 * 4 + 1][cg];
        const float* w2 = &Ws[k4 * 4 + 2][cg];
        const float* w3 = &Ws[k4 * 4 + 3][cg];
#pragma unroll
        for (int j = 0; j < 32; ++j) acc[j] += a.x * w0[4 * j];
#pragma unroll
        for (int j = 0; j < 32; ++j) acc[j] += a.y * w1[4 * j];
#pragma unroll
        for (int j = 0; j < 32; ++j) acc[j] += a.z * w2[4 * j];
#pragma unroll
        for (int j = 0; j < 32; ++j) acc[j] += a.w * w3[4 * j];
    }

    const float inv = rsqrtf(1.f + 1e-5f);
    float* op = out + (size_t)row * DIM;
#pragma unroll
    for (int j = 0; j < 32; ++j) {
        const int col = 4 * j + cg;
        float v = acc[j] + b[col];
        if (BN) v = v * (inv * g[col]) + bt[col];
        op[col] = fmaxf(v, 0.f);
    }
}

// ---------------------------------------------------------------------------
// zero a small buffer
__global__ void zero_f(float* p, int n) {
    int i = blockIdx.x * blockDim.x + threadIdx.x;
    if (i < n) p[i] = 0.f;
}

// sum-pool: pooled[batch[n]] += x[n]  (32 threads/node, float4)
__global__ void pool_nodes(float* __restrict__ pooled, const float* __restrict__ x,
                           const int* __restrict__ batch, int n) {
    int idx = blockIdx.x * blockDim.x + threadIdx.x;
    int node = idx >> 5;
    if (node >= n) return;
    int q = idx & 31;
    int gidx = batch[node];
    const float4 v = ((const float4*)(x + (size_t)node * DIM))[q];
    float* p = pooled + (size_t)gidx * DIM + (q << 2);
    atomicAdd(p + 0, v.x);
    atomicAdd(p + 1, v.y);
    atomicAdd(p + 2, v.z);
    atomicAdd(p + 3, v.w);
}

// ---------------------------------------------------------------------------
// final MLP layer 1: hidden[g][c] = relu((pooled[g]·mW1[:,c] + mb1[c])*inv*mg[c] + mbt[c])
__global__ void final1(float* __restrict__ hidden, const float* __restrict__ pooled,
                       const float* __restrict__ W, const float* __restrict__ b,
                       const float* __restrict__ g, const float* __restrict__ bt) {
    int idx = blockIdx.x * blockDim.x + threadIdx.x;  // N_GRAPHS*DIM
    if (idx >= N_GRAPHS * DIM) return;
    int row = idx >> 7;
    int col = idx & 127;
    float s = 0.f;
    for (int k = 0; k < DIM; ++k) s += pooled[row * DIM + k] * W[k * DIM + col];
    const float inv = rsqrtf(1.f + 1e-5f);
    s = (s + b[col]) * (inv * g[col]) + bt[col];
    hidden[idx] = fmaxf(s, 0.f);
}

// final MLP layer 2 (plain): out[g][o] = hidden[g]·mW2[:,o] + mb2[o]
__global__ void final2(float* __restrict__ out, const float* __restrict__ hidden,
                       const float* __restrict__ W, const float* __restrict__ b) {
    int idx = blockIdx.x * blockDim.x + threadIdx.x;  // N_GRAPHS*NOUT
    if (idx >= N_GRAPHS * NOUT) return;
    int row = idx / NOUT;
    int col = idx % NOUT;
    float s = 0.f;
    for (int k = 0; k < DIM; ++k) s += hidden[row * DIM + k] * W[k * NOUT + col];
    out[idx] = s + b[col];
}

// ---------------------------------------------------------------------------
extern "C" void kernel_launch(void* const* d_in, const int* in_sizes, int n_in,
                              void* d_out, int out_size, void* d_ws, size_t ws_size,
                              hipStream_t stream) {
    const float* x      = (const float*)d_in[0];
    const int*   ei     = (const int*)d_in[1];   // [2, N_EDGES]
    const int*   batch  = (const int*)d_in[2];
    const float* convW1 = (const float*)d_in[3];
    const float* convb1 = (const float*)d_in[4];
    const float* convg  = (const float*)d_in[5];
    const float* convbt = (const float*)d_in[6];
    const float* convW2 = (const float*)d_in[7];
    const float* convb2 = (const float*)d_in[8];
    const float* mW1    = (const float*)d_in[9];
    const float* mb1    = (const float*)d_in[10];
    const float* mg     = (const float*)d_in[11];
    const float* mbt    = (const float*)d_in[12];
    const float* mW2    = (const float*)d_in[13];
    const float* mb2    = (const float*)d_in[14];
    float* out = (float*)d_out;

    const int* srcs = ei;
    const int* dsts = ei + N_EDGES;

    // workspace layout
    const size_t NF = (size_t)N_NODES * DIM;  // 6.4M floats
    float* xbuf   = (float*)d_ws;             // layer output
    float* aggbuf = xbuf + NF;
    float* h1buf  = aggbuf + NF;
    float* pooled = h1buf + NF;               // 128*128
    float* hidden = pooled + N_GRAPHS * DIM;  // 128*128

    const int n4 = (int)(NF / 4);
    const int copyBlocks    = (n4 + 255) / 256;
    const int scatterBlocks = (N_EDGES * 32 + 255) / 256;
    const int gemmBlocks    = (N_NODES + 63) / 64;
    const int poolBlocks    = (N_NODES * 32 + 255) / 256;

    const float* cur = x;
    for (int l = 0; l < NLAYERS; ++l) {
        // agg = cur
        copy_f4<<<copyBlocks, 256, 0, stream>>>((float4*)aggbuf, (const float4*)cur, n4);
        // agg += scatter(cur[src] -> dst)
        scatter_edges<<<scatterBlocks, 256, 0, stream>>>(aggbuf, cur, srcs, dsts, N_EDGES);
        // h1 = relu(BN(agg @ W1 + b1))
        gemm_fused<true><<<gemmBlocks, 256, 0, stream>>>(
            h1buf, aggbuf, convW1 + (size_t)l * DIM * DIM, convb1 + l * DIM,
            convg + l * DIM, convbt + l * DIM, N_NODES);
        // xbuf = relu(h1 @ W2 + b2)
        gemm_fused<false><<<gemmBlocks, 256, 0, stream>>>(
            xbuf, h1buf, convW2 + (size_t)l * DIM * DIM, convb2 + l * DIM,
            nullptr, nullptr, N_NODES);
        cur = xbuf;
    }

    // pooled = segment_sum(xbuf, batch)
    zero_f<<<(N_GRAPHS * DIM + 255) / 256, 256, 0, stream>>>(pooled, N_GRAPHS * DIM);
    pool_nodes<<<poolBlocks, 256, 0, stream>>>(pooled, cur, batch, N_NODES);

    // final MLP
    final1<<<(N_GRAPHS * DIM + 255) / 256, 256, 0, stream>>>(hidden, pooled, mW1, mb1, mg, mbt);
    final2<<<(N_GRAPHS * NOUT + 255) / 256, 256, 0, stream>>>(out, hidden, mW2, mb2);
}

// Round 2
// 1057.764 us; speedup vs baseline: 3.8183x; 3.8183x over previous
//
#include <hip/hip_runtime.h>

#define N_NODES 50000
#define N_EDGES 600000
#define N_GRAPHS 128
#define DIM 128
#define NLAYERS 3
#define NOUT 10

// ---------------------------------------------------------------------------
// zero an int buffer
__global__ void zero_i(int* p, int n) {
    int i = blockIdx.x * blockDim.x + threadIdx.x;
    if (i < n) p[i] = 0;
}

// degree histogram: deg[dst[e]]++
__global__ void hist_deg(int* __restrict__ deg, const int* __restrict__ dsts, int nE) {
    int e = blockIdx.x * blockDim.x + threadIdx.x;
    if (e < nE) atomicAdd(&deg[dsts[e]], 1);
}

// per-64-chunk inclusive wave scan of deg; chunk totals to sums[]
__global__ void scan_chunks(int* __restrict__ partial, int* __restrict__ sums,
                            const int* __restrict__ deg, int n) {
    int i = blockIdx.x * blockDim.x + threadIdx.x;
    int lane = threadIdx.x & 63;
    int v = (i < n) ? deg[i] : 0;
#pragma unroll
    for (int off = 1; off < 64; off <<= 1) {
        int t = __shfl_up(v, off);
        if (lane >= off) v += t;
    }
    if (i < n) partial[i] = v;
    if (lane == 63) sums[i >> 6] = v;  // sums has slack for tail chunks
}

// single-wave exclusive scan of chunk sums
__global__ void scan_sums(int* __restrict__ offs, const int* __restrict__ sums, int nc) {
    int lane = threadIdx.x;  // 64 threads
    int carry = 0;
    for (int base = 0; base < nc; base += 64) {
        int idx = base + lane;
        int v = (idx < nc) ? sums[idx] : 0;
        int inc = v;
#pragma unroll
        for (int off = 1; off < 64; off <<= 1) {
            int t = __shfl_up(inc, off);
            if (lane >= off) inc += t;
        }
        if (idx < nc) offs[idx] = inc - v + carry;  // exclusive
        carry += __shfl(inc, 63);
    }
}

// rowptr[i+1] = inclusive[i]; cursor[i] = exclusive start; rowptr[0]=0
__global__ void finalize_rowptr(int* __restrict__ rowptr, int* __restrict__ cursor,
                                const int* __restrict__ partial, const int* __restrict__ offs,
                                const int* __restrict__ deg, int n) {
    int i = blockIdx.x * blockDim.x + threadIdx.x;
    if (i == 0) rowptr[0] = 0;
    if (i < n) {
        int incl = partial[i] + offs[i >> 6];
        rowptr[i + 1] = incl;
        cursor[i] = incl - deg[i];
    }
}

// scatter edges into CSR slots (int atomics on cursors only)
__global__ void fill_csr(int* __restrict__ csr, int* __restrict__ cursor,
                         const int* __restrict__ srcs, const int* __restrict__ dsts, int nE) {
    int e = blockIdx.x * blockDim.x + threadIdx.x;
    if (e >= nE) return;
    int d = dsts[e];
    int p = atomicAdd(&cursor[d], 1);
    csr[p] = srcs[e];
}

// ---------------------------------------------------------------------------
// gather: agg[n] = x[n] + sum_{j in csr row n} x[csr[j]]
// one wave per node, float2 per lane (64*8B = full 512B row)
__global__ __launch_bounds__(256) void gather_csr(float* __restrict__ agg,
                                                  const float* __restrict__ x,
                                                  const int* __restrict__ rowptr,
                                                  const int* __restrict__ csr, int nNodes) {
    int wid = (blockIdx.x * 256 + threadIdx.x) >> 6;
    int lane = threadIdx.x & 63;
    if (wid >= nNodes) return;
    const size_t rowoff = (size_t)wid * DIM + lane * 2;
    float2 acc = *(const float2*)(x + rowoff);
    int beg = rowptr[wid], end = rowptr[wid + 1];
    int j = beg;
    for (; j + 4 <= end; j += 4) {
        int s0 = csr[j], s1 = csr[j + 1], s2 = csr[j + 2], s3 = csr[j + 3];
        float2 v0 = *(const float2*)(x + (size_t)s0 * DIM + lane * 2);
        float2 v1 = *(const float2*)(x + (size_t)s1 * DIM + lane * 2);
        float2 v2 = *(const float2*)(x + (size_t)s2 * DIM + lane * 2);
        float2 v3 = *(const float2*)(x + (size_t)s3 * DIM + lane * 2);
        acc.x += (v0.x + v1.x) + (v2.x + v3.x);
        acc.y += (v0.y + v1.y) + (v2.y + v3.y);
    }
    for (; j < end; ++j) {
        int s = csr[j];
        float2 v = *(const float2*)(x + (size_t)s * DIM + lane * 2);
        acc.x += v.x;
        acc.y += v.y;
    }
    *(float2*)(agg + rowoff) = acc;
}

// ---------------------------------------------------------------------------
// Fused GEMM: out[n][c] = relu((in[n]·W[:,c] + b[c]) [* (inv*g[c]) + bt[c]])
template <bool BN>
__global__ __launch_bounds__(256) void gemm_fused(float* __restrict__ out,
                                                  const float* __restrict__ in,
                                                  const float* __restrict__ W,
                                                  const float* __restrict__ b,
                                                  const float* __restrict__ g,
                                                  const float* __restrict__ bt,
                                                  int nrows) {
    __shared__ float Ws[DIM][DIM];  // 64 KB
    {
        const float4* W4 = (const float4*)W;
        float4* Ws4 = (float4*)&Ws[0][0];
        for (int i = threadIdx.x; i < DIM * DIM / 4; i += 256) Ws4[i] = W4[i];
    }
    __syncthreads();

    const int row = blockIdx.x * 64 + (threadIdx.x >> 2);
    const int cg = threadIdx.x & 3;
    if (row >= nrows) return;

    const float4* in4 = (const float4*)(in + (size_t)row * DIM);
    float acc[32];
#pragma unroll
    for (int j = 0; j < 32; ++j) acc[j] = 0.f;

#pragma unroll 4
    for (int k4 = 0; k4 < 32; ++k4) {
        const float4 a = in4[k4];
        const float* w0 = &Ws[k4 * 4 + 0][cg];
        const float* w1 = &Ws[k4 * 4 + 1][cg];
        const float* w2 = &Ws[k4 * 4 + 2][cg];
        const float* w3 = &Ws[k4 * 4 + 3][cg];
#pragma unroll
        for (int j = 0; j < 32; ++j) acc[j] += a.x * w0[4 * j];
#pragma unroll
        for (int j = 0; j < 32; ++j) acc[j] += a.y * w1[4 * j];
#pragma unroll
        for (int j = 0; j < 32; ++j) acc[j] += a.z * w2[4 * j];
#pragma unroll
        for (int j = 0; j < 32; ++j) acc[j] += a.w * w3[4 * j];
    }

    const float inv = rsqrtf(1.f + 1e-5f);
    float* op = out + (size_t)row * DIM;
#pragma unroll
    for (int j = 0; j < 32; ++j) {
        const int col = 4 * j + cg;
        float v = acc[j] + b[col];
        if (BN) v = v * (inv * g[col]) + bt[col];
        op[col] = fmaxf(v, 0.f);
    }
}

// ---------------------------------------------------------------------------
// block-per-graph sum pool (batch is sorted): 128 threads, one column each
__global__ __launch_bounds__(128) void pool_graphs(float* __restrict__ pooled,
                                                   const float* __restrict__ x,
                                                   const int* __restrict__ batch) {
    const int g = blockIdx.x;
    const int c = threadIdx.x;
    __shared__ int sbeg, send;
    if (c == 0) {
        int lo = 0, hi = N_NODES;
        while (lo < hi) { int m = (lo + hi) >> 1; if (batch[m] < g) lo = m + 1; else hi = m; }
        sbeg = lo;
        lo = 0; hi = N_NODES;
        while (lo < hi) { int m = (lo + hi) >> 1; if (batch[m] < g + 1) lo = m + 1; else hi = m; }
        send = lo;
    }
    __syncthreads();
    float acc = 0.f;
    int n = sbeg;
    for (; n + 4 <= send; n += 4) {
        acc += x[(size_t)n * DIM + c] + x[(size_t)(n + 1) * DIM + c] +
               x[(size_t)(n + 2) * DIM + c] + x[(size_t)(n + 3) * DIM + c];
    }
    for (; n < send; ++n) acc += x[(size_t)n * DIM + c];
    pooled[g * DIM + c] = acc;
}

// ---------------------------------------------------------------------------
__global__ void final1(float* __restrict__ hidden, const float* __restrict__ pooled,
                       const float* __restrict__ W, const float* __restrict__ b,
                       const float* __restrict__ g, const float* __restrict__ bt) {
    int idx = blockIdx.x * blockDim.x + threadIdx.x;
    if (idx >= N_GRAPHS * DIM) return;
    int row = idx >> 7;
    int col = idx & 127;
    float s = 0.f;
    for (int k = 0; k < DIM; ++k) s += pooled[row * DIM + k] * W[k * DIM + col];
    const float inv = rsqrtf(1.f + 1e-5f);
    s = (s + b[col]) * (inv * g[col]) + bt[col];
    hidden[idx] = fmaxf(s, 0.f);
}

__global__ void final2(float* __restrict__ out, const float* __restrict__ hidden,
                       const float* __restrict__ W, const float* __restrict__ b) {
    int idx = blockIdx.x * blockDim.x + threadIdx.x;
    if (idx >= N_GRAPHS * NOUT) return;
    int row = idx / NOUT;
    int col = idx % NOUT;
    float s = 0.f;
    for (int k = 0; k < DIM; ++k) s += hidden[row * DIM + k] * W[k * NOUT + col];
    out[idx] = s + b[col];
}

// ---------------------------------------------------------------------------
extern "C" void kernel_launch(void* const* d_in, const int* in_sizes, int n_in,
                              void* d_out, int out_size, void* d_ws, size_t ws_size,
                              hipStream_t stream) {
    const float* x      = (const float*)d_in[0];
    const int*   ei     = (const int*)d_in[1];
    const int*   batch  = (const int*)d_in[2];
    const float* convW1 = (const float*)d_in[3];
    const float* convb1 = (const float*)d_in[4];
    const float* convg  = (const float*)d_in[5];
    const float* convbt = (const float*)d_in[6];
    const float* convW2 = (const float*)d_in[7];
    const float* convb2 = (const float*)d_in[8];
    const float* mW1    = (const float*)d_in[9];
    const float* mb1    = (const float*)d_in[10];
    const float* mg     = (const float*)d_in[11];
    const float* mbt    = (const float*)d_in[12];
    const float* mW2    = (const float*)d_in[13];
    const float* mb2    = (const float*)d_in[14];
    float* out = (float*)d_out;

    const int* srcs = ei;
    const int* dsts = ei + N_EDGES;

    // workspace layout
    const size_t NF = (size_t)N_NODES * DIM;
    float* xbuf   = (float*)d_ws;
    float* aggbuf = xbuf + NF;
    float* h1buf  = aggbuf + NF;
    float* pooled = h1buf + NF;
    float* hidden = pooled + N_GRAPHS * DIM;
    int*   deg     = (int*)(hidden + N_GRAPHS * DIM);
    int*   cursor  = deg + N_NODES;
    int*   rowptr  = cursor + N_NODES;          // N_NODES+1
    int*   partial = rowptr + (N_NODES + 1);
    int*   sums    = partial + N_NODES;          // 1024 w/ slack
    int*   offs    = sums + 1024;                // 1024
    int*   csr     = offs + 1024;                // N_EDGES

    const int NCHUNK = (N_NODES + 63) / 64;

    // ---- CSR build (once per call; edge_index constant across layers) ----
    zero_i<<<(N_NODES + 255) / 256, 256, 0, stream>>>(deg, N_NODES);
    hist_deg<<<(N_EDGES + 255) / 256, 256, 0, stream>>>(deg, dsts, N_EDGES);
    scan_chunks<<<(N_NODES + 255) / 256, 256, 0, stream>>>(partial, sums, deg, N_NODES);
    scan_sums<<<1, 64, 0, stream>>>(offs, sums, NCHUNK);
    finalize_rowptr<<<(N_NODES + 255) / 256, 256, 0, stream>>>(rowptr, cursor, partial, offs, deg, N_NODES);
    fill_csr<<<(N_EDGES + 255) / 256, 256, 0, stream>>>(csr, cursor, srcs, dsts, N_EDGES);

    const int gatherBlocks = (N_NODES * 64 + 255) / 256;
    const int gemmBlocks   = (N_NODES + 63) / 64;

    const float* cur = x;
    for (int l = 0; l < NLAYERS; ++l) {
        gather_csr<<<gatherBlocks, 256, 0, stream>>>(aggbuf, cur, rowptr, csr, N_NODES);
        gemm_fused<true><<<gemmBlocks, 256, 0, stream>>>(
            h1buf, aggbuf, convW1 + (size_t)l * DIM * DIM, convb1 + l * DIM,
            convg + l * DIM, convbt + l * DIM, N_NODES);
        gemm_fused<false><<<gemmBlocks, 256, 0, stream>>>(
            xbuf, h1buf, convW2 + (size_t)l * DIM * DIM, convb2 + l * DIM,
            nullptr, nullptr, N_NODES);
        cur = xbuf;
    }

    pool_graphs<<<N_GRAPHS, 128, 0, stream>>>(pooled, cur, batch);
    final1<<<(N_GRAPHS * DIM + 127) / 128, 128, 0, stream>>>(hidden, pooled, mW1, mb1, mg, mbt);
    final2<<<(N_GRAPHS * NOUT + 127) / 128, 128, 0, stream>>>(out, hidden, mW2, mb2);
}

// Round 3
// 471.308 us; speedup vs baseline: 8.5695x; 2.2443x over previous
//
#include <hip/hip_runtime.h>

#define N_NODES 50000
#define N_EDGES 600000
#define N_GRAPHS 128
#define DIM 128
#define NLAYERS 3
#define NOUT 10

// ---------------------------------------------------------------------------
__global__ void zero_i(int* p, int n) {
    int i = blockIdx.x * blockDim.x + threadIdx.x;
    if (i < n) p[i] = 0;
}

__global__ void hist_deg(int* __restrict__ deg, const int* __restrict__ dsts, int nE) {
    int e = blockIdx.x * blockDim.x + threadIdx.x;
    if (e < nE) atomicAdd(&deg[dsts[e]], 1);
}

__global__ void scan_chunks(int* __restrict__ partial, int* __restrict__ sums,
                            const int* __restrict__ deg, int n) {
    int i = blockIdx.x * blockDim.x + threadIdx.x;
    int lane = threadIdx.x & 63;
    int v = (i < n) ? deg[i] : 0;
#pragma unroll
    for (int off = 1; off < 64; off <<= 1) {
        int t = __shfl_up(v, off);
        if (lane >= off) v += t;
    }
    if (i < n) partial[i] = v;
    if (lane == 63) sums[i >> 6] = v;
}

__global__ void scan_sums(int* __restrict__ offs, const int* __restrict__ sums, int nc) {
    int lane = threadIdx.x;  // 64 threads
    int carry = 0;
    for (int base = 0; base < nc; base += 64) {
        int idx = base + lane;
        int v = (idx < nc) ? sums[idx] : 0;
        int inc = v;
#pragma unroll
        for (int off = 1; off < 64; off <<= 1) {
            int t = __shfl_up(inc, off);
            if (lane >= off) inc += t;
        }
        if (idx < nc) offs[idx] = inc - v + carry;
        carry += __shfl(inc, 63);
    }
}

__global__ void finalize_rowptr(int* __restrict__ rowptr, int* __restrict__ cursor,
                                const int* __restrict__ partial, const int* __restrict__ offs,
                                const int* __restrict__ deg, int n) {
    int i = blockIdx.x * blockDim.x + threadIdx.x;
    if (i == 0) rowptr[0] = 0;
    if (i < n) {
        int incl = partial[i] + offs[i >> 6];
        rowptr[i + 1] = incl;
        cursor[i] = incl - deg[i];
    }
}

__global__ void fill_csr(int* __restrict__ csr, int* __restrict__ cursor,
                         const int* __restrict__ srcs, const int* __restrict__ dsts, int nE) {
    int e = blockIdx.x * blockDim.x + threadIdx.x;
    if (e >= nE) return;
    int d = dsts[e];
    int p = atomicAdd(&cursor[d], 1);
    csr[p] = srcs[e];
}

// ---------------------------------------------------------------------------
// gather: agg[n] = x[n] + sum_{j in csr row n} x[csr[j]]   (one wave per node)
__global__ __launch_bounds__(256) void gather_csr(float* __restrict__ agg,
                                                  const float* __restrict__ x,
                                                  const int* __restrict__ rowptr,
                                                  const int* __restrict__ csr, int nNodes) {
    int wid = (blockIdx.x * 256 + threadIdx.x) >> 6;
    int lane = threadIdx.x & 63;
    if (wid >= nNodes) return;
    const size_t rowoff = (size_t)wid * DIM + lane * 2;
    float2 acc = *(const float2*)(x + rowoff);
    int beg = rowptr[wid], end = rowptr[wid + 1];
    int j = beg;
    for (; j + 4 <= end; j += 4) {
        int s0 = csr[j], s1 = csr[j + 1], s2 = csr[j + 2], s3 = csr[j + 3];
        float2 v0 = *(const float2*)(x + (size_t)s0 * DIM + lane * 2);
        float2 v1 = *(const float2*)(x + (size_t)s1 * DIM + lane * 2);
        float2 v2 = *(const float2*)(x + (size_t)s2 * DIM + lane * 2);
        float2 v3 = *(const float2*)(x + (size_t)s3 * DIM + lane * 2);
        acc.x += (v0.x + v1.x) + (v2.x + v3.x);
        acc.y += (v0.y + v1.y) + (v2.y + v3.y);
    }
    for (; j < end; ++j) {
        int s = csr[j];
        float2 v = *(const float2*)(x + (size_t)s * DIM + lane * 2);
        acc.x += v.x;
        acc.y += v.y;
    }
    *(float2*)(agg + rowoff) = acc;
}

// ---------------------------------------------------------------------------
// Register-blocked fused GEMM: out = relu([BN](in @ W + b))
// Block 256 = 4 waves; block tile 64 rows x 128 cols.
// Wave w: rows w*16..w*16+15 (broadcast from LDS A^T), lane owns cols {2l,2l+1}.
// Per k: 4 broadcast ds_read_b128 (A) + 1 global float2 (W) + 32 FMA -> VALU-bound.
template <bool BN>
__global__ __launch_bounds__(256, 4) void gemm_rb(float* __restrict__ out,
                                                  const float* __restrict__ in,
                                                  const float* __restrict__ W,
                                                  const float* __restrict__ b,
                                                  const float* __restrict__ g,
                                                  const float* __restrict__ bt,
                                                  int nrows) {
    __shared__ float Ast[DIM][68];  // [k][r], padded: 34.8 KB -> 4 blocks/CU
    const int tid = threadIdx.x;
    const int row0 = blockIdx.x * 64;

    // ---- stage A^T (coalesced global b128, <=2-way-conflict LDS writes) ----
    {
        const int r = tid >> 2;   // 0..63
        const int kb = tid & 3;   // 0..3
        const int grow = row0 + r;
        const bool valid = grow < nrows;
        const float4* src = (const float4*)(in + (size_t)grow * DIM);
#pragma unroll
        for (int i = 0; i < 8; ++i) {
            const int k0 = i * 16 + kb * 4;
            float4 v = valid ? src[k0 >> 2] : make_float4(0.f, 0.f, 0.f, 0.f);
            Ast[k0 + 0][r] = v.x;
            Ast[k0 + 1][r] = v.y;
            Ast[k0 + 2][r] = v.z;
            Ast[k0 + 3][r] = v.w;
        }
    }
    __syncthreads();

    const int wv = tid >> 6;
    const int lane = tid & 63;
    const int r0 = wv * 16;
    const int c0 = lane * 2;
    const float* Wp = W + c0;

    float acc[16][2];
#pragma unroll
    for (int i = 0; i < 16; ++i) { acc[i][0] = 0.f; acc[i][1] = 0.f; }

    float2 wreg[4];
#pragma unroll
    for (int j = 0; j < 4; ++j) wreg[j] = *(const float2*)(Wp + j * DIM);

    for (int k0 = 0; k0 < DIM; k0 += 4) {
        const int kn = (k0 + 4) & (DIM - 1);  // wrap on last iter (harmless reload)
        float2 wnext[4];
#pragma unroll
        for (int j = 0; j < 4; ++j) wnext[j] = *(const float2*)(Wp + (kn + j) * DIM);
#pragma unroll
        for (int j = 0; j < 4; ++j) {
            const int k = k0 + j;
            float4 a[4];
            a[0] = *(const float4*)&Ast[k][r0 + 0];
            a[1] = *(const float4*)&Ast[k][r0 + 4];
            a[2] = *(const float4*)&Ast[k][r0 + 8];
            a[3] = *(const float4*)&Ast[k][r0 + 12];
            const float2 w = wreg[j];
#pragma unroll
            for (int q = 0; q < 4; ++q) {
                acc[q * 4 + 0][0] += a[q].x * w.x; acc[q * 4 + 0][1] += a[q].x * w.y;
                acc[q * 4 + 1][0] += a[q].y * w.x; acc[q * 4 + 1][1] += a[q].y * w.y;
                acc[q * 4 + 2][0] += a[q].z * w.x; acc[q * 4 + 2][1] += a[q].z * w.y;
                acc[q * 4 + 3][0] += a[q].w * w.x; acc[q * 4 + 3][1] += a[q].w * w.y;
            }
        }
#pragma unroll
        for (int j = 0; j < 4; ++j) wreg[j] = wnext[j];
    }

    // ---- epilogue ----
    const float inv = rsqrtf(1.f + 1e-5f);
    const float2 bb = *(const float2*)&b[c0];
    float2 gg = make_float2(0.f, 0.f), tt = make_float2(0.f, 0.f);
    if (BN) { gg = *(const float2*)&g[c0]; tt = *(const float2*)&bt[c0]; }
#pragma unroll
    for (int rq = 0; rq < 16; ++rq) {
        const int grow = row0 + r0 + rq;
        if (grow < nrows) {
            float v0 = acc[rq][0] + bb.x;
            float v1 = acc[rq][1] + bb.y;
            if (BN) { v0 = v0 * (inv * gg.x) + tt.x; v1 = v1 * (inv * gg.y) + tt.y; }
            *(float2*)(out + (size_t)grow * DIM + c0) = make_float2(fmaxf(v0, 0.f), fmaxf(v1, 0.f));
        }
    }
}

// ---------------------------------------------------------------------------
__global__ __launch_bounds__(128) void pool_graphs(float* __restrict__ pooled,
                                                   const float* __restrict__ x,
                                                   const int* __restrict__ batch) {
    const int g = blockIdx.x;
    const int c = threadIdx.x;
    __shared__ int sbeg, send;
    if (c == 0) {
        int lo = 0, hi = N_NODES;
        while (lo < hi) { int m = (lo + hi) >> 1; if (batch[m] < g) lo = m + 1; else hi = m; }
        sbeg = lo;
        lo = 0; hi = N_NODES;
        while (lo < hi) { int m = (lo + hi) >> 1; if (batch[m] < g + 1) lo = m + 1; else hi = m; }
        send = lo;
    }
    __syncthreads();
    float acc = 0.f;
    int n = sbeg;
    for (; n + 4 <= send; n += 4) {
        acc += x[(size_t)n * DIM + c] + x[(size_t)(n + 1) * DIM + c] +
               x[(size_t)(n + 2) * DIM + c] + x[(size_t)(n + 3) * DIM + c];
    }
    for (; n < send; ++n) acc += x[(size_t)n * DIM + c];
    pooled[g * DIM + c] = acc;
}

// ---------------------------------------------------------------------------
__global__ void final1(float* __restrict__ hidden, const float* __restrict__ pooled,
                       const float* __restrict__ W, const float* __restrict__ b,
                       const float* __restrict__ g, const float* __restrict__ bt) {
    int idx = blockIdx.x * blockDim.x + threadIdx.x;
    if (idx >= N_GRAPHS * DIM) return;
    int row = idx >> 7;
    int col = idx & 127;
    float s = 0.f;
    for (int k = 0; k < DIM; ++k) s += pooled[row * DIM + k] * W[k * DIM + col];
    const float inv = rsqrtf(1.f + 1e-5f);
    s = (s + b[col]) * (inv * g[col]) + bt[col];
    hidden[idx] = fmaxf(s, 0.f);
}

__global__ void final2(float* __restrict__ out, const float* __restrict__ hidden,
                       const float* __restrict__ W, const float* __restrict__ b) {
    int idx = blockIdx.x * blockDim.x + threadIdx.x;
    if (idx >= N_GRAPHS * NOUT) return;
    int row = idx / NOUT;
    int col = idx % NOUT;
    float s = 0.f;
    for (int k = 0; k < DIM; ++k) s += hidden[row * DIM + k] * W[k * NOUT + col];
    out[idx] = s + b[col];
}

// ---------------------------------------------------------------------------
extern "C" void kernel_launch(void* const* d_in, const int* in_sizes, int n_in,
                              void* d_out, int out_size, void* d_ws, size_t ws_size,
                              hipStream_t stream) {
    const float* x      = (const float*)d_in[0];
    const int*   ei     = (const int*)d_in[1];
    const int*   batch  = (const int*)d_in[2];
    const float* convW1 = (const float*)d_in[3];
    const float* convb1 = (const float*)d_in[4];
    const float* convg  = (const float*)d_in[5];
    const float* convbt = (const float*)d_in[6];
    const float* convW2 = (const float*)d_in[7];
    const float* convb2 = (const float*)d_in[8];
    const float* mW1    = (const float*)d_in[9];
    const float* mb1    = (const float*)d_in[10];
    const float* mg     = (const float*)d_in[11];
    const float* mbt    = (const float*)d_in[12];
    const float* mW2    = (const float*)d_in[13];
    const float* mb2    = (const float*)d_in[14];
    float* out = (float*)d_out;

    const int* srcs = ei;
    const int* dsts = ei + N_EDGES;

    const size_t NF = (size_t)N_NODES * DIM;
    float* xbuf   = (float*)d_ws;
    float* aggbuf = xbuf + NF;
    float* h1buf  = aggbuf + NF;
    float* pooled = h1buf + NF;
    float* hidden = pooled + N_GRAPHS * DIM;
    int*   deg     = (int*)(hidden + N_GRAPHS * DIM);
    int*   cursor  = deg + N_NODES;
    int*   rowptr  = cursor + N_NODES;
    int*   partial = rowptr + (N_NODES + 1);
    int*   sums    = partial + N_NODES;
    int*   offs    = sums + 1024;
    int*   csr     = offs + 1024;

    const int NCHUNK = (N_NODES + 63) / 64;

    // ---- CSR build ----
    zero_i<<<(N_NODES + 255) / 256, 256, 0, stream>>>(deg, N_NODES);
    hist_deg<<<(N_EDGES + 255) / 256, 256, 0, stream>>>(deg, dsts, N_EDGES);
    scan_chunks<<<(N_NODES + 255) / 256, 256, 0, stream>>>(partial, sums, deg, N_NODES);
    scan_sums<<<1, 64, 0, stream>>>(offs, sums, NCHUNK);
    finalize_rowptr<<<(N_NODES + 255) / 256, 256, 0, stream>>>(rowptr, cursor, partial, offs, deg, N_NODES);
    fill_csr<<<(N_EDGES + 255) / 256, 256, 0, stream>>>(csr, cursor, srcs, dsts, N_EDGES);

    const int gatherBlocks = (N_NODES * 64 + 255) / 256;
    const int gemmBlocks   = (N_NODES + 63) / 64;

    const float* cur = x;
    for (int l = 0; l < NLAYERS; ++l) {
        gather_csr<<<gatherBlocks, 256, 0, stream>>>(aggbuf, cur, rowptr, csr, N_NODES);
        gemm_rb<true><<<gemmBlocks, 256, 0, stream>>>(
            h1buf, aggbuf, convW1 + (size_t)l * DIM * DIM, convb1 + l * DIM,
            convg + l * DIM, convbt + l * DIM, N_NODES);
        gemm_rb<false><<<gemmBlocks, 256, 0, stream>>>(
            xbuf, h1buf, convW2 + (size_t)l * DIM * DIM, convb2 + l * DIM,
            nullptr, nullptr, N_NODES);
        cur = xbuf;
    }

    pool_graphs<<<N_GRAPHS, 128, 0, stream>>>(pooled, cur, batch);
    final1<<<(N_GRAPHS * DIM + 127) / 128, 128, 0, stream>>>(hidden, pooled, mW1, mb1, mg, mbt);
    final2<<<(N_GRAPHS * NOUT + 127) / 128, 128, 0, stream>>>(out, hidden, mW2, mb2);
}

// Round 4
// 297.118 us; speedup vs baseline: 13.5935x; 1.5863x over previous
//
#include <hip/hip_runtime.h>

#define N_NODES 50000
#define N_EDGES 600000
#define N_GRAPHS 128
#define DIM 128
#define NLAYERS 3
#define NOUT 10

typedef unsigned short u16;
typedef __attribute__((ext_vector_type(8))) short bf16x8;
typedef __attribute__((ext_vector_type(4))) float f32x4;

__device__ __forceinline__ float bf2f(u16 v) {
    unsigned u = ((unsigned)v) << 16;
    return __builtin_bit_cast(float, u);
}
__device__ __forceinline__ u16 f2bf(float f) {  // round-to-nearest-even
    unsigned u = __builtin_bit_cast(unsigned, f);
    u = u + 0x7fffu + ((u >> 16) & 1u);
    return (u16)(u >> 16);
}

// ---------------------------------------------------------------------------
__global__ void zero_i(int* p, int n) {
    int i = blockIdx.x * blockDim.x + threadIdx.x;
    if (i < n) p[i] = 0;
}

__global__ void hist_deg(int* __restrict__ deg, const int* __restrict__ dsts, int nE) {
    int e = blockIdx.x * blockDim.x + threadIdx.x;
    if (e < nE) atomicAdd(&deg[dsts[e]], 1);
}

__global__ void scan_chunks(int* __restrict__ partial, int* __restrict__ sums,
                            const int* __restrict__ deg, int n) {
    int i = blockIdx.x * blockDim.x + threadIdx.x;
    int lane = threadIdx.x & 63;
    int v = (i < n) ? deg[i] : 0;
#pragma unroll
    for (int off = 1; off < 64; off <<= 1) {
        int t = __shfl_up(v, off);
        if (lane >= off) v += t;
    }
    if (i < n) partial[i] = v;
    if (lane == 63) sums[i >> 6] = v;
}

__global__ void scan_sums(int* __restrict__ offs, const int* __restrict__ sums, int nc) {
    int lane = threadIdx.x;  // 64 threads
    int carry = 0;
    for (int base = 0; base < nc; base += 64) {
        int idx = base + lane;
        int v = (idx < nc) ? sums[idx] : 0;
        int inc = v;
#pragma unroll
        for (int off = 1; off < 64; off <<= 1) {
            int t = __shfl_up(inc, off);
            if (lane >= off) inc += t;
        }
        if (idx < nc) offs[idx] = inc - v + carry;
        carry += __shfl(inc, 63);
    }
}

__global__ void finalize_rowptr(int* __restrict__ rowptr, int* __restrict__ cursor,
                                const int* __restrict__ partial, const int* __restrict__ offs,
                                const int* __restrict__ deg, int n) {
    int i = blockIdx.x * blockDim.x + threadIdx.x;
    if (i == 0) rowptr[0] = 0;
    if (i < n) {
        int incl = partial[i] + offs[i >> 6];
        rowptr[i + 1] = incl;
        cursor[i] = incl - deg[i];
    }
}

__global__ void fill_csr(int* __restrict__ csr, int* __restrict__ cursor,
                         const int* __restrict__ srcs, const int* __restrict__ dsts, int nE) {
    int e = blockIdx.x * blockDim.x + threadIdx.x;
    if (e >= nE) return;
    int d = dsts[e];
    int p = atomicAdd(&cursor[d], 1);
    csr[p] = srcs[e];
}

// ---------------------------------------------------------------------------
// x (f32) -> bf16
__global__ void cvt_bf16(u16* __restrict__ dst, const float* __restrict__ src, int n4) {
    int i = blockIdx.x * blockDim.x + threadIdx.x;
    if (i >= n4) return;
    float4 v = ((const float4*)src)[i];
    ushort4 o;
    o.x = f2bf(v.x); o.y = f2bf(v.y); o.z = f2bf(v.z); o.w = f2bf(v.w);
    ((ushort4*)dst)[i] = o;
}

// Pre-swizzle the 6 conv weight matrices (f32 row-major [k][c]) into MFMA
// B-fragment order: Wswz[mat][kc][cb][lane][j] = W[kc*32+(lane>>4)*8+j][cb*16+(lane&15)]
__global__ void wprep(u16* __restrict__ Wswz, const float* __restrict__ convW1,
                      const float* __restrict__ convW2) {
    int i = blockIdx.x * blockDim.x + threadIdx.x;  // < 6*16384
    if (i >= 6 * 16384) return;
    int j = i & 7, lane = (i >> 3) & 63, cb = (i >> 9) & 7, kc = (i >> 12) & 3, w = i >> 14;
    int k = kc * 32 + ((lane >> 4) << 3) + j;
    int c = (cb << 4) + (lane & 15);
    const float* W = (w < 3) ? (convW1 + (size_t)w * 16384) : (convW2 + (size_t)(w - 3) * 16384);
    Wswz[i] = f2bf(W[k * DIM + c]);
}

// ---------------------------------------------------------------------------
// gather (bf16): agg[n] = x[n] + sum_{j in csr row n} x[csr[j]]  (one wave/node)
__global__ __launch_bounds__(256) void gather_bf(u16* __restrict__ agg,
                                                 const u16* __restrict__ x,
                                                 const int* __restrict__ rowptr,
                                                 const int* __restrict__ csr, int nNodes) {
    int wid = (blockIdx.x * 256 + threadIdx.x) >> 6;
    int lane = threadIdx.x & 63;
    if (wid >= nNodes) return;
    const size_t coff = (size_t)lane * 2;
    ushort2 self = *(const ushort2*)(x + (size_t)wid * DIM + coff);
    float ax = bf2f(self.x), ay = bf2f(self.y);
    int beg = rowptr[wid], end = rowptr[wid + 1];
    int j = beg;
    for (; j + 4 <= end; j += 4) {
        int s0 = csr[j], s1 = csr[j + 1], s2 = csr[j + 2], s3 = csr[j + 3];
        ushort2 v0 = *(const ushort2*)(x + (size_t)s0 * DIM + coff);
        ushort2 v1 = *(const ushort2*)(x + (size_t)s1 * DIM + coff);
        ushort2 v2 = *(const ushort2*)(x + (size_t)s2 * DIM + coff);
        ushort2 v3 = *(const ushort2*)(x + (size_t)s3 * DIM + coff);
        ax += (bf2f(v0.x) + bf2f(v1.x)) + (bf2f(v2.x) + bf2f(v3.x));
        ay += (bf2f(v0.y) + bf2f(v1.y)) + (bf2f(v2.y) + bf2f(v3.y));
    }
    for (; j < end; ++j) {
        int s = csr[j];
        ushort2 v = *(const ushort2*)(x + (size_t)s * DIM + coff);
        ax += bf2f(v.x);
        ay += bf2f(v.y);
    }
    ushort2 o; o.x = f2bf(ax); o.y = f2bf(ay);
    *(ushort2*)(agg + (size_t)wid * DIM + coff) = o;
}

// ---------------------------------------------------------------------------
// MFMA fused GEMM: out = relu([BN](in @ W + b)), in/out bf16, acc f32.
// Block 256 = 4 waves x 16 rows = 64 rows x 128 cols.
// B (W) pre-swizzled in global, staged 32 KB to LDS; frag = ds_read_b128.
// A frags straight from global (16B/lane). C/D: col=lane&15, row=(lane>>4)*4+q.
template <bool BN>
__global__ __launch_bounds__(256) void gemm_mfma(u16* __restrict__ out,
                                                 const u16* __restrict__ in,
                                                 const u16* __restrict__ Wswz,
                                                 const float* __restrict__ b,
                                                 const float* __restrict__ g,
                                                 const float* __restrict__ bt,
                                                 int nrows) {
    __shared__ u16 Bs[16384];  // 32 KB
    {
        float4* d = (float4*)Bs;
        const float4* s = (const float4*)Wswz;
        for (int i = threadIdx.x; i < 2048; i += 256) d[i] = s[i];
    }
    __syncthreads();

    const int wv = threadIdx.x >> 6;
    const int lane = threadIdx.x & 63;
    const int row0 = blockIdx.x * 64 + wv * 16;

    const int arow = min(row0 + (lane & 15), nrows - 1);
    const u16* ap = in + (size_t)arow * DIM + ((lane >> 4) << 3);
    bf16x8 a[4];
#pragma unroll
    for (int kc = 0; kc < 4; ++kc) a[kc] = *(const bf16x8*)(ap + kc * 32);

    f32x4 acc[8];
#pragma unroll
    for (int cb = 0; cb < 8; ++cb) acc[cb] = (f32x4){0.f, 0.f, 0.f, 0.f};

#pragma unroll
    for (int kc = 0; kc < 4; ++kc) {
#pragma unroll
        for (int cb = 0; cb < 8; ++cb) {
            bf16x8 bb = *(const bf16x8*)&Bs[(((kc << 3) + cb) << 6 | lane) << 3];
            acc[cb] = __builtin_amdgcn_mfma_f32_16x16x32_bf16(a[kc], bb, acc[cb], 0, 0, 0);
        }
    }

    const float inv = rsqrtf(1.f + 1e-5f);
    const int col0 = lane & 15;
    const int rbase = row0 + ((lane >> 4) << 2);
#pragma unroll
    for (int cb = 0; cb < 8; ++cb) {
        const int c = (cb << 4) + col0;
        const float bias = b[c];
        float sg = 0.f, st = 0.f;
        if (BN) { sg = inv * g[c]; st = bt[c]; }
#pragma unroll
        for (int q = 0; q < 4; ++q) {
            const int r = rbase + q;
            if (r < nrows) {
                float v = acc[cb][q] + bias;
                if (BN) v = v * sg + st;
                out[(size_t)r * DIM + c] = f2bf(fmaxf(v, 0.f));
            }
        }
    }
}

// ---------------------------------------------------------------------------
// block-per-graph sum pool (batch sorted), bf16 in, f32 out
__global__ __launch_bounds__(128) void pool_graphs(float* __restrict__ pooled,
                                                   const u16* __restrict__ x,
                                                   const int* __restrict__ batch) {
    const int g = blockIdx.x;
    const int c = threadIdx.x;
    __shared__ int sbeg, send;
    if (c == 0) {
        int lo = 0, hi = N_NODES;
        while (lo < hi) { int m = (lo + hi) >> 1; if (batch[m] < g) lo = m + 1; else hi = m; }
        sbeg = lo;
        lo = 0; hi = N_NODES;
        while (lo < hi) { int m = (lo + hi) >> 1; if (batch[m] < g + 1) lo = m + 1; else hi = m; }
        send = lo;
    }
    __syncthreads();
    float acc = 0.f;
    int n = sbeg;
    for (; n + 4 <= send; n += 4) {
        acc += bf2f(x[(size_t)n * DIM + c]) + bf2f(x[(size_t)(n + 1) * DIM + c]) +
               bf2f(x[(size_t)(n + 2) * DIM + c]) + bf2f(x[(size_t)(n + 3) * DIM + c]);
    }
    for (; n < send; ++n) acc += bf2f(x[(size_t)n * DIM + c]);
    pooled[g * DIM + c] = acc;
}

// ---------------------------------------------------------------------------
__global__ void final1(float* __restrict__ hidden, const float* __restrict__ pooled,
                       const float* __restrict__ W, const float* __restrict__ b,
                       const float* __restrict__ g, const float* __restrict__ bt) {
    int idx = blockIdx.x * blockDim.x + threadIdx.x;
    if (idx >= N_GRAPHS * DIM) return;
    int row = idx >> 7;
    int col = idx & 127;
    float s = 0.f;
    for (int k = 0; k < DIM; ++k) s += pooled[row * DIM + k] * W[k * DIM + col];
    const float inv = rsqrtf(1.f + 1e-5f);
    s = (s + b[col]) * (inv * g[col]) + bt[col];
    hidden[idx] = fmaxf(s, 0.f);
}

__global__ void final2(float* __restrict__ out, const float* __restrict__ hidden,
                       const float* __restrict__ W, const float* __restrict__ b) {
    int idx = blockIdx.x * blockDim.x + threadIdx.x;
    if (idx >= N_GRAPHS * NOUT) return;
    int row = idx / NOUT;
    int col = idx % NOUT;
    float s = 0.f;
    for (int k = 0; k < DIM; ++k) s += hidden[row * DIM + k] * W[k * NOUT + col];
    out[idx] = s + b[col];
}

// ---------------------------------------------------------------------------
extern "C" void kernel_launch(void* const* d_in, const int* in_sizes, int n_in,
                              void* d_out, int out_size, void* d_ws, size_t ws_size,
                              hipStream_t stream) {
    const float* x      = (const float*)d_in[0];
    const int*   ei     = (const int*)d_in[1];
    const int*   batch  = (const int*)d_in[2];
    const float* convW1 = (const float*)d_in[3];
    const float* convb1 = (const float*)d_in[4];
    const float* convg  = (const float*)d_in[5];
    const float* convbt = (const float*)d_in[6];
    const float* convW2 = (const float*)d_in[7];
    const float* convb2 = (const float*)d_in[8];
    const float* mW1    = (const float*)d_in[9];
    const float* mb1    = (const float*)d_in[10];
    const float* mg     = (const float*)d_in[11];
    const float* mbt    = (const float*)d_in[12];
    const float* mW2    = (const float*)d_in[13];
    const float* mb2    = (const float*)d_in[14];
    float* out = (float*)d_out;

    const int* srcs = ei;
    const int* dsts = ei + N_EDGES;

    // workspace layout
    const size_t NF = (size_t)N_NODES * DIM;  // 6.4M elems
    u16* xb0    = (u16*)d_ws;                 // bf16 x
    u16* xbuf   = xb0 + NF;
    u16* aggbuf = xbuf + NF;
    u16* h1buf  = aggbuf + NF;
    u16* Wswz   = h1buf + NF;                 // 6*16384 bf16
    float* pooled = (float*)(Wswz + 6 * 16384);
    float* hidden = pooled + N_GRAPHS * DIM;
    int*   deg     = (int*)(hidden + N_GRAPHS * DIM);
    int*   cursor  = deg + N_NODES;
    int*   rowptr  = cursor + N_NODES;
    int*   partial = rowptr + (N_NODES + 1);
    int*   sums    = partial + N_NODES;
    int*   offs    = sums + 1024;
    int*   csr     = offs + 1024;

    const int NCHUNK = (N_NODES + 63) / 64;

    // ---- CSR build + conversions ----
    zero_i<<<(N_NODES + 255) / 256, 256, 0, stream>>>(deg, N_NODES);
    hist_deg<<<(N_EDGES + 255) / 256, 256, 0, stream>>>(deg, dsts, N_EDGES);
    scan_chunks<<<(N_NODES + 255) / 256, 256, 0, stream>>>(partial, sums, deg, N_NODES);
    scan_sums<<<1, 64, 0, stream>>>(offs, sums, NCHUNK);
    finalize_rowptr<<<(N_NODES + 255) / 256, 256, 0, stream>>>(rowptr, cursor, partial, offs, deg, N_NODES);
    fill_csr<<<(N_EDGES + 255) / 256, 256, 0, stream>>>(csr, cursor, srcs, dsts, N_EDGES);
    cvt_bf16<<<((int)(NF / 4) + 255) / 256, 256, 0, stream>>>(xb0, x, (int)(NF / 4));
    wprep<<<(6 * 16384 + 255) / 256, 256, 0, stream>>>(Wswz, convW1, convW2);

    const int gatherBlocks = (N_NODES * 64 + 255) / 256;
    const int gemmBlocks   = (N_NODES + 63) / 64;

    const u16* cur = xb0;
    for (int l = 0; l < NLAYERS; ++l) {
        gather_bf<<<gatherBlocks, 256, 0, stream>>>(aggbuf, cur, rowptr, csr, N_NODES);
        gemm_mfma<true><<<gemmBlocks, 256, 0, stream>>>(
            h1buf, aggbuf, Wswz + (size_t)l * 16384, convb1 + l * DIM,
            convg + l * DIM, convbt + l * DIM, N_NODES);
        gemm_mfma<false><<<gemmBlocks, 256, 0, stream>>>(
            xbuf, h1buf, Wswz + (size_t)(3 + l) * 16384, convb2 + l * DIM,
            nullptr, nullptr, N_NODES);
        cur = xbuf;
    }

    pool_graphs<<<N_GRAPHS, 128, 0, stream>>>(pooled, cur, batch);
    final1<<<(N_GRAPHS * DIM + 127) / 128, 128, 0, stream>>>(hidden, pooled, mW1, mb1, mg, mbt);
    final2<<<(N_GRAPHS * NOUT + 127) / 128, 128, 0, stream>>>(out, hidden, mW2, mb2);
}